// Round 16
// baseline (369.788 us; speedup 1.0000x reference)
//
#include <hip/hip_runtime.h>
#include <stdint.h>

typedef unsigned short u16;
typedef float f32x4 __attribute__((ext_vector_type(4)));
typedef short bf16x8 __attribute__((ext_vector_type(8)));

// ---------- helpers ----------
static __device__ __forceinline__ u16 f2bf(float f) {
  union { float f; unsigned u; } a; a.f = f;
  unsigned r = a.u + 0x7fffu + ((a.u >> 16) & 1u);   // round-nearest-even
  return (u16)(r >> 16);
}

static __device__ __forceinline__ void gld16(const void* g, void* l) {
  __builtin_amdgcn_global_load_lds(
      (const __attribute__((address_space(1))) void*)(uintptr_t)g,
      (__attribute__((address_space(3))) void*)(uintptr_t)l,
      16, 0, 0);
}

// ================== K1: all input-only work, INTERLEAVED segments ==================
// r15 post-mortem: contiguous bid->segment mapping clusters the heavy gate blocks
// (393KB traffic each = 2/3 of dispatch bytes in 1/6 of blocks) -> gate-only tail.
// Fix: round-robin bid%6 -> {1 gate, 4 Waug-cast, 1 A-cast} so every CU carries a
// balanced traffic mix.  Segment BODIES byte-identical to r15 (proven); only the
// bid->work mapping changes.  __launch_bounds__(256,4) caps VGPR at 128 (proven).
__global__ __launch_bounds__(256, 4) void fused_pre(
    const float* __restrict__ x, const float* __restrict__ Wg,
    const float* __restrict__ Wb, const float* __restrict__ B,
    const float* __restrict__ A,
    u16* __restrict__ Xaug, u16* __restrict__ Waug, u16* __restrict__ a2,
    float* __restrict__ wsc) {
  const int bid = blockIdx.x;          // 3072 blocks
  const int seg = bid % 6;
  const int sid = bid / 6;             // 0..511 within segment group
  const int t = threadIdx.x;
  if (seg == 0) {
    // ---- cast x + gate, 4 tokens/wave (512 blocks) ----
    const int lane = t & 63;
    const int wv = t >> 6;
    const int n0 = sid * 16 + wv * 4;
    const float4* g4 = (const float4*)Wg;      // [8][1024] float4
    float acc[4][8] = {};
#pragma unroll 2
    for (int ii = 0; ii < 16; ++ii) {
      const int i = ii * 64 + lane;
      float4 xv[4];
#pragma unroll
      for (int tok = 0; tok < 4; ++tok) {
        xv[tok] = *(const float4*)(x + (size_t)(n0 + tok) * 4096 + i * 4);
        ushort4 o;
        o.x = f2bf(xv[tok].x); o.y = f2bf(xv[tok].y);
        o.z = f2bf(xv[tok].z); o.w = f2bf(xv[tok].w);
        *(ushort4*)(Xaug + (size_t)(n0 + tok) * 4224 + i * 4) = o;
      }
#pragma unroll
      for (int e = 0; e < 8; ++e) {
        float4 w4 = g4[e * 1024 + i];
#pragma unroll
        for (int tok = 0; tok < 4; ++tok)
          acc[tok][e] += xv[tok].x * w4.x + xv[tok].y * w4.y +
                         xv[tok].z * w4.z + xv[tok].w * w4.w;
      }
    }
#pragma unroll
    for (int tok = 0; tok < 4; ++tok) {
#pragma unroll
      for (int e = 0; e < 8; ++e) {
#pragma unroll
        for (int off = 32; off > 0; off >>= 1)
          acc[tok][e] += __shfl_xor(acc[tok][e], off);
      }
      int i1 = 0; float m1 = acc[tok][0];
#pragma unroll
      for (int e = 1; e < 8; ++e) if (acc[tok][e] > m1) { m1 = acc[tok][e]; i1 = e; }
      int i2 = -1; float m2 = -3.4e38f;
#pragma unroll
      for (int e = 0; e < 8; ++e)
        if (e != i1 && acc[tok][e] > m2) { m2 = acc[tok][e]; i2 = e; }
      float w1 = 1.0f / (1.0f + expf(m2 - m1));   // p1/(p1+p2) softmax+renorm
      float w2 = 1.0f - w1;
      if (lane < 8)
        wsc[(size_t)(n0 + tok) * 8 + lane] =
            (lane == i1) ? w1 : ((lane == i2) ? w2 : 0.0f);
    }
  } else if (seg <= 4) {
    // ---- cast Wb + B -> Waug (2048 blocks, grid-stride) ----
    const int cid = sid * 4 + (seg - 1);         // 0..2047
    const int total = 4096 * 1056;               // vec4 groups
    for (int v = cid * 256 + t; v < total; v += 2048 * 256) {
      const int o = v / 1056;
      const int c = (v - o * 1056) * 4;
      ushort4 out;
      if (c < 4096) {
        float4 w = *(const float4*)(Wb + (size_t)o * 4096 + c);
        out.x = f2bf(w.x); out.y = f2bf(w.y); out.z = f2bf(w.z); out.w = f2bf(w.w);
      } else {
        const int er = c - 4096;
        const int e = er >> 4;
        const int r = er & 15;
        const float* bp = B + ((size_t)e * 4096 + o) * 16 + r;
        out.x = f2bf(bp[0] * 2.0f); out.y = f2bf(bp[1] * 2.0f);
        out.z = f2bf(bp[2] * 2.0f); out.w = f2bf(bp[3] * 2.0f);
      }
      *(ushort4*)(Waug + (size_t)o * 4224 + c) = out;
    }
  } else {
    // ---- cast A -> a2 (512 blocks) ----
    const int i = sid * 256 + t;                 // 0..131071 vec4 groups
    const size_t e = (size_t)i * 4;
    float4 v = *(const float4*)(A + e);
    ushort4 o;
    o.x = f2bf(v.x); o.y = f2bf(v.y); o.z = f2bf(v.z); o.w = f2bf(v.w);
    *(ushort4*)(a2 + e) = o;
  }
}

// ================== K2: LoRA down-proj + gate-scale (verbatim r12/r15, proven) ==================
__global__ __launch_bounds__(256) void lora_hw(
    const u16* __restrict__ Xa, const u16* __restrict__ A2,
    const float* __restrict__ wsc, u16* __restrict__ Xaug) {
  __shared__ __align__(1024) char lds[40960];
  const int t = threadIdx.x;
  const int lane = t & 63;
  const int w = t >> 6;               // 0..3, wave's 32-col strip
  const int l15 = lane & 15, lhi = lane >> 4;
  const int brow = blockIdx.x * 32;

  const int sb = (lane << 4) ^ (lane & 32);
  const int srow = sb >> 6;
  const int scol = (sb & 63) >> 1;

  const u16* pA = Xa + (size_t)(brow + (w >> 1) * 16 + srow) * 4224 + (w & 1) * 32 + scol;
  const u16* pB[4];
#pragma unroll
  for (int s = 0; s < 4; ++s) {
    const int idx = w * 4 + s;
    pB[s] = A2 + (size_t)((idx >> 1) * 16 + srow) * 4096 + (idx & 1) * 32 + scol;
  }
  const int dA = w << 10;
  const int dB = 4096 + (w << 12);
  const int innerL = ((l15 << 6) + (lhi << 4)) ^ ((l15 & 8) << 2);

  f32x4 acc[2][2] = {};

  gld16(pA, lds + dA);
#pragma unroll
  for (int s = 0; s < 4; ++s) gld16(pB[s], lds + dB + (s << 10));

  for (int j = 0; j < 64; ++j) {
    const int buf = (j & 1) * 20480;
    const int obuf = buf ^ 20480;
    if (j < 63) {
      const int k1 = (j + 1) * 64;
      gld16(pA + k1, lds + obuf + dA);
#pragma unroll
      for (int s = 0; s < 4; ++s) gld16(pB[s] + k1, lds + obuf + dB + (s << 10));
      asm volatile("s_waitcnt vmcnt(5)" ::: "memory");   // tile j landed
    } else {
      asm volatile("s_waitcnt vmcnt(0)" ::: "memory");
    }
    __syncthreads();
    bf16x8 av[2][2], bv[2][2];
#pragma unroll
    for (int m = 0; m < 2; ++m)
#pragma unroll
      for (int kk = 0; kk < 2; ++kk)
        av[m][kk] = *(const bf16x8*)(lds + buf + ((m * 2 + kk) << 10) + innerL);
#pragma unroll
    for (int n = 0; n < 2; ++n)
#pragma unroll
      for (int kk = 0; kk < 2; ++kk)
        bv[n][kk] = *(const bf16x8*)(lds + buf + 4096 + (((w * 2 + n) * 2 + kk) << 10) + innerL);
#pragma unroll
    for (int kk = 0; kk < 2; ++kk)
#pragma unroll
      for (int m = 0; m < 2; ++m)
#pragma unroll
        for (int n = 0; n < 2; ++n)
          acc[m][n] = __builtin_amdgcn_mfma_f32_16x16x32_bf16(av[m][kk], bv[n][kk], acc[m][n], 0, 0, 0);
    __syncthreads();
  }
#pragma unroll
  for (int m = 0; m < 2; ++m) {
    const int rbase = brow + m * 16 + lhi * 4;
#pragma unroll
    for (int n = 0; n < 2; ++n) {
      const int col = w * 32 + n * 16 + l15;
#pragma unroll
      for (int j = 0; j < 4; ++j) {
        const int row = rbase + j;
        const float g = wsc[(size_t)row * 8 + (col >> 4)];
        Xaug[(size_t)row * 4224 + 4096 + col] = f2bf(acc[m][n][j] * g);
      }
    }
  }
}

// ================== 256x256 main GEMM (r12 EXACT — proven 236us control) ==================
#define BAR do { asm volatile("" ::: "memory"); __builtin_amdgcn_s_barrier(); asm volatile("" ::: "memory"); } while (0)

#define RDA(BUF, MH)                                                            \
  { _Pragma("unroll") for (int mm = 0; mm < 4; ++mm)                            \
    _Pragma("unroll") for (int kk = 0; kk < 2; ++kk)                            \
      av[mm][kk] = *(const bf16x8*)(lds + (BUF) + fbA + ((((MH) * 4 + mm) * 2 + kk) << 10)); }

#define RDB(BUF, NH)                                                            \
  { _Pragma("unroll") for (int nn = 0; nn < 2; ++nn)                            \
    _Pragma("unroll") for (int kk = 0; kk < 2; ++kk)                            \
      bv[(NH) * 2 + nn][kk] = *(const bf16x8*)(lds + (BUF) + fbB + ((((NH) * 2 + nn) * 2 + kk) << 10)); }

#define MFMAQ(MH, NH)                                                           \
  { __builtin_amdgcn_s_setprio(1);                                              \
    _Pragma("unroll") for (int kk = 0; kk < 2; ++kk)                            \
    _Pragma("unroll") for (int mm = 0; mm < 4; ++mm)                            \
    _Pragma("unroll") for (int nn = 0; nn < 2; ++nn)                            \
      acc[(MH) * 4 + mm][(NH) * 2 + nn] = __builtin_amdgcn_mfma_f32_16x16x32_bf16( \
          av[mm][kk], bv[(NH) * 2 + nn][kk], acc[(MH) * 4 + mm][(NH) * 2 + nn], 0, 0, 0); \
    __builtin_amdgcn_s_setprio(0); }

__global__ __launch_bounds__(512, 2) void gemm8p(
    const u16* __restrict__ Ag, const u16* __restrict__ Bg,
    const float* __restrict__ bias, float* __restrict__ C,
    int lda, int ldb, int ldc, int K) {
  __shared__ __align__(1024) char lds[131072];
  const int t = threadIdx.x;
  const int lane = t & 63;
  const int w = t >> 6;
  const int wr = w >> 2, wc = w & 3;
  const int l15 = lane & 15, lhi = lane >> 4;

  const int bid = blockIdx.x;
  const int g = bid >> 3;
  const int tile_m = (bid & 7) * 4 + (g & 3);
  const int tile_n = g >> 2;
  const int brow = tile_m << 8;
  const int bcol = tile_n << 8;

  const int sb = (lane << 4) ^ (lane & 32);
  const int srow = sb >> 6;
  const int scol = (sb & 63) >> 1;

  const u16* pA[4]; const u16* pB[4];
#pragma unroll
  for (int s = 0; s < 4; ++s) {
    const int idx = w * 4 + s;
    const int rg = idx >> 1, cs = idx & 1;
    pA[s] = Ag + (size_t)(brow + rg * 16 + srow) * lda + cs * 32 + scol;
    pB[s] = Bg + (size_t)(bcol + rg * 16 + srow) * ldb + cs * 32 + scol;
  }
  const int ldsA = w << 12;
  const int ldsB = 32768 + (w << 12);

  const int innerL = ((l15 << 6) + (lhi << 4)) ^ ((l15 & 8) << 2);
  const int fbA = (wr << 14) + innerL;
  const int fbB = 32768 + (wc << 13) + innerL;

  f32x4 acc[8][4] = {};
  bf16x8 av[4][2], bv[4][2];

  const int NT = K >> 6;   // 66 K-tiles

#pragma unroll
  for (int s = 0; s < 4; ++s) gld16(pA[s], lds + ldsA + (s << 10));
#pragma unroll
  for (int s = 0; s < 4; ++s) gld16(pB[s], lds + ldsB + (s << 10));
#pragma unroll
  for (int s = 0; s < 4; ++s) gld16(pB[s] + 64, lds + 65536 + ldsB + (s << 10));
#pragma unroll
  for (int s = 0; s < 4; ++s) { pA[s] += 64; pB[s] += 128; }
  asm volatile("s_waitcnt vmcnt(4)" ::: "memory");   // A(0),B(0) landed
  BAR;
  RDA(0, 0); RDB(0, 0);    // av0(0), bv01(0) for first M0

  for (int j = 0; j < NT; ++j) {
    const int buf  = (j & 1) << 16;
    const int obuf = buf ^ 65536;
    const bool stA = (j + 1 < NT);
    const bool stB = (j + 2 < NT);
    // p0: stage A(j+1)[0,1]; M0 [av0,bv01]; read bv23 (regs free)
    if (stA) { gld16(pA[0], lds + obuf + ldsA);
               gld16(pA[1], lds + obuf + ldsA + 1024); }
    MFMAQ(0, 0);
    RDB(buf, 1);
    BAR;
    // p1: stage A(j+1)[2,3]; M1 [av0,bv23]; read av1
    if (stA) { gld16(pA[2], lds + obuf + ldsA + 2048);
               gld16(pA[3], lds + obuf + ldsA + 3072); }
    MFMAQ(0, 1);
    RDA(buf, 1);
    BAR;
    // p2: stage B(j+2)[0,1] -> this buf; M2
    if (stB) { gld16(pB[0], lds + buf + ldsB);
               gld16(pB[1], lds + buf + ldsB + 1024); }
    MFMAQ(1, 1);
    BAR;
    // p3: stage B(j+2)[2,3]; vmcnt(4)+BAR; M3; read av0',bv01' from next buf
    if (stB) { gld16(pB[2], lds + buf + ldsB + 2048);
               gld16(pB[3], lds + buf + ldsB + 3072); }
    if (j < NT - 2)       { asm volatile("s_waitcnt vmcnt(4)" ::: "memory"); }
    else if (j == NT - 2) { asm volatile("s_waitcnt vmcnt(0)" ::: "memory"); }
    BAR;
    MFMAQ(1, 0);
    if (stA) { RDA(obuf, 0); RDB(obuf, 0); }
#pragma unroll
    for (int s = 0; s < 4; ++s) { pA[s] += 64; pB[s] += 64; }
  }

#pragma unroll
  for (int m = 0; m < 8; ++m) {
    const int row0 = brow + wr * 128 + m * 16 + lhi * 4;
#pragma unroll
    for (int n = 0; n < 4; ++n) {
      const int col = bcol + wc * 64 + n * 16 + l15;
      const float b2 = bias[col];
#pragma unroll
      for (int jj = 0; jj < 4; ++jj)
        C[(size_t)(row0 + jj) * ldc + col] = acc[m][n][jj] + b2;
    }
  }
}

// ---------- launch ----------
extern "C" void kernel_launch(void* const* d_in, const int* in_sizes, int n_in,
                              void* d_out, int out_size, void* d_ws, size_t ws_size,
                              hipStream_t stream) {
  const float* x  = (const float*)d_in[0];   // [8192][4096]
  const float* Wb = (const float*)d_in[1];   // [4096][4096]
  const float* bb = (const float*)d_in[2];   // [4096]
  const float* Wg = (const float*)d_in[3];   // [8][4096]
  const float* A  = (const float*)d_in[4];   // [8][16][4096] = [128][4096]
  const float* B  = (const float*)d_in[5];   // [8][4096][16]
  float* out = (float*)d_out;                // [8192][4096]

  char* ws = (char*)d_ws;
  u16*   Xaug = (u16*)ws;                                     // 8192 x 4224 bf16
  u16*   Waug = (u16*)(ws + 69206016);                        // 4096 x 4224 bf16
  u16*   a2   = (u16*)(ws + 69206016 + 34603008);             // 128 x 4096 bf16
  float* wsc  = (float*)(ws + 69206016 + 34603008 + 1048576); // 8192 x 8

  // 1) all input-only work, segments interleaved per-bid for traffic balance
  fused_pre<<<3072, 256, 0, stream>>>(x, Wg, Wb, B, A, Xaug, Waug, a2, wsc);

  // 2) lora down-proj + gate-scale (only kernel depending on step 1)
  lora_hw<<<256, 256, 0, stream>>>(Xaug, a2, wsc, Xaug);

  // 3) main fused GEMM: out = Xaug @ Waug^T + bias (r12 proven schedule)
  gemm8p<<<512, 512, 0, stream>>>(Xaug, Waug, bb, out, 4224, 4224, 4096, 4224);
}

// Round 17
// 338.935 us; speedup vs baseline: 1.0910x; 1.0910x over previous
//
#include <hip/hip_runtime.h>
#include <stdint.h>

typedef unsigned short u16;
typedef float f32x4 __attribute__((ext_vector_type(4)));
typedef short bf16x8 __attribute__((ext_vector_type(8)));

// ---------- helpers ----------
static __device__ __forceinline__ u16 f2bf(float f) {
  union { float f; unsigned u; } a; a.f = f;
  unsigned r = a.u + 0x7fffu + ((a.u >> 16) & 1u);   // round-nearest-even
  return (u16)(r >> 16);
}

static __device__ __forceinline__ void gld16(const void* g, void* l) {
  __builtin_amdgcn_global_load_lds(
      (const __attribute__((address_space(1))) void*)(uintptr_t)g,
      (__attribute__((address_space(3))) void*)(uintptr_t)l,
      16, 0, 0);
}

// ================== K1: all input-only work (VERBATIM r15 — best, 331us) ==================
__global__ __launch_bounds__(256, 4) void fused_pre(
    const float* __restrict__ x, const float* __restrict__ Wg,
    const float* __restrict__ Wb, const float* __restrict__ B,
    const float* __restrict__ A,
    u16* __restrict__ Xaug, u16* __restrict__ Waug, u16* __restrict__ a2,
    float* __restrict__ wsc) {
  const int bid = blockIdx.x;
  const int t = threadIdx.x;
  if (bid < 512) {
    const int lane = t & 63;
    const int wv = t >> 6;
    const int n0 = bid * 16 + wv * 4;
    const float4* g4 = (const float4*)Wg;      // [8][1024] float4
    float acc[4][8] = {};
#pragma unroll 2
    for (int ii = 0; ii < 16; ++ii) {
      const int i = ii * 64 + lane;
      float4 xv[4];
#pragma unroll
      for (int tok = 0; tok < 4; ++tok) {
        xv[tok] = *(const float4*)(x + (size_t)(n0 + tok) * 4096 + i * 4);
        ushort4 o;
        o.x = f2bf(xv[tok].x); o.y = f2bf(xv[tok].y);
        o.z = f2bf(xv[tok].z); o.w = f2bf(xv[tok].w);
        *(ushort4*)(Xaug + (size_t)(n0 + tok) * 4224 + i * 4) = o;
      }
#pragma unroll
      for (int e = 0; e < 8; ++e) {
        float4 w4 = g4[e * 1024 + i];
#pragma unroll
        for (int tok = 0; tok < 4; ++tok)
          acc[tok][e] += xv[tok].x * w4.x + xv[tok].y * w4.y +
                         xv[tok].z * w4.z + xv[tok].w * w4.w;
      }
    }
#pragma unroll
    for (int tok = 0; tok < 4; ++tok) {
#pragma unroll
      for (int e = 0; e < 8; ++e) {
#pragma unroll
        for (int off = 32; off > 0; off >>= 1)
          acc[tok][e] += __shfl_xor(acc[tok][e], off);
      }
      int i1 = 0; float m1 = acc[tok][0];
#pragma unroll
      for (int e = 1; e < 8; ++e) if (acc[tok][e] > m1) { m1 = acc[tok][e]; i1 = e; }
      int i2 = -1; float m2 = -3.4e38f;
#pragma unroll
      for (int e = 0; e < 8; ++e)
        if (e != i1 && acc[tok][e] > m2) { m2 = acc[tok][e]; i2 = e; }
      float w1 = 1.0f / (1.0f + expf(m2 - m1));   // p1/(p1+p2) softmax+renorm
      float w2 = 1.0f - w1;
      if (lane < 8)
        wsc[(size_t)(n0 + tok) * 8 + lane] =
            (lane == i1) ? w1 : ((lane == i2) ? w2 : 0.0f);
    }
  } else if (bid < 2560) {
    const int total = 4096 * 1056;               // vec4 groups
    for (int v = (bid - 512) * 256 + t; v < total; v += 2048 * 256) {
      const int o = v / 1056;
      const int c = (v - o * 1056) * 4;
      ushort4 out;
      if (c < 4096) {
        float4 w = *(const float4*)(Wb + (size_t)o * 4096 + c);
        out.x = f2bf(w.x); out.y = f2bf(w.y); out.z = f2bf(w.z); out.w = f2bf(w.w);
      } else {
        const int er = c - 4096;
        const int e = er >> 4;
        const int r = er & 15;
        const float* bp = B + ((size_t)e * 4096 + o) * 16 + r;
        out.x = f2bf(bp[0] * 2.0f); out.y = f2bf(bp[1] * 2.0f);
        out.z = f2bf(bp[2] * 2.0f); out.w = f2bf(bp[3] * 2.0f);
      }
      *(ushort4*)(Waug + (size_t)o * 4224 + c) = out;
    }
  } else {
    const int i = (bid - 2560) * 256 + t;        // 0..131071 vec4 groups
    const size_t e = (size_t)i * 4;
    float4 v = *(const float4*)(A + e);
    ushort4 o;
    o.x = f2bf(v.x); o.y = f2bf(v.y); o.z = f2bf(v.z); o.w = f2bf(v.w);
    *(ushort4*)(a2 + e) = o;
  }
}

// ================== K2: LoRA down-proj + gate-scale (VERBATIM r15, proven) ==================
__global__ __launch_bounds__(256) void lora_hw(
    const u16* __restrict__ Xa, const u16* __restrict__ A2,
    const float* __restrict__ wsc, u16* __restrict__ Xaug) {
  __shared__ __align__(1024) char lds[40960];
  const int t = threadIdx.x;
  const int lane = t & 63;
  const int w = t >> 6;
  const int l15 = lane & 15, lhi = lane >> 4;
  const int brow = blockIdx.x * 32;

  const int sb = (lane << 4) ^ (lane & 32);
  const int srow = sb >> 6;
  const int scol = (sb & 63) >> 1;

  const u16* pA = Xa + (size_t)(brow + (w >> 1) * 16 + srow) * 4224 + (w & 1) * 32 + scol;
  const u16* pB[4];
#pragma unroll
  for (int s = 0; s < 4; ++s) {
    const int idx = w * 4 + s;
    pB[s] = A2 + (size_t)((idx >> 1) * 16 + srow) * 4096 + (idx & 1) * 32 + scol;
  }
  const int dA = w << 10;
  const int dB = 4096 + (w << 12);
  const int innerL = ((l15 << 6) + (lhi << 4)) ^ ((l15 & 8) << 2);

  f32x4 acc[2][2] = {};

  gld16(pA, lds + dA);
#pragma unroll
  for (int s = 0; s < 4; ++s) gld16(pB[s], lds + dB + (s << 10));

  for (int j = 0; j < 64; ++j) {
    const int buf = (j & 1) * 20480;
    const int obuf = buf ^ 20480;
    if (j < 63) {
      const int k1 = (j + 1) * 64;
      gld16(pA + k1, lds + obuf + dA);
#pragma unroll
      for (int s = 0; s < 4; ++s) gld16(pB[s] + k1, lds + obuf + dB + (s << 10));
      asm volatile("s_waitcnt vmcnt(5)" ::: "memory");   // tile j landed
    } else {
      asm volatile("s_waitcnt vmcnt(0)" ::: "memory");
    }
    __syncthreads();
    bf16x8 av[2][2], bv[2][2];
#pragma unroll
    for (int m = 0; m < 2; ++m)
#pragma unroll
      for (int kk = 0; kk < 2; ++kk)
        av[m][kk] = *(const bf16x8*)(lds + buf + ((m * 2 + kk) << 10) + innerL);
#pragma unroll
    for (int n = 0; n < 2; ++n)
#pragma unroll
      for (int kk = 0; kk < 2; ++kk)
        bv[n][kk] = *(const bf16x8*)(lds + buf + 4096 + (((w * 2 + n) * 2 + kk) << 10) + innerL);
#pragma unroll
    for (int kk = 0; kk < 2; ++kk)
#pragma unroll
      for (int m = 0; m < 2; ++m)
#pragma unroll
        for (int n = 0; n < 2; ++n)
          acc[m][n] = __builtin_amdgcn_mfma_f32_16x16x32_bf16(av[m][kk], bv[n][kk], acc[m][n], 0, 0, 0);
    __syncthreads();
  }
#pragma unroll
  for (int m = 0; m < 2; ++m) {
    const int rbase = brow + m * 16 + lhi * 4;
#pragma unroll
    for (int n = 0; n < 2; ++n) {
      const int col = w * 32 + n * 16 + l15;
#pragma unroll
      for (int j = 0; j < 4; ++j) {
        const int row = rbase + j;
        const float g = wsc[(size_t)row * 8 + (col >> 4)];
        Xaug[(size_t)row * 4224 + 4096 + col] = f2bf(acc[m][n][j] * g);
      }
    }
  }
}

// ================== 256x256 main GEMM — faithful m201 8-phase port ==================
// 2 K-tiles/iter (e=2i dbuf0 @0, o=2i+1 dbuf1 @65536).  Each dbuf: A-lo 0, A-hi
// 16K, B-lo 32K, B-hi 48K (16KB halves of 128 rows/cols x 64 k).  Wave output
// remap: row = mh*128 + wr*64 + m*16, col = nh*128 + wc*32 + n*16 -> EVERY wave
// reads A-lo,B-lo @p0; B-hi @p1; A-hi @p2 (quadrant order Q00,Q01,Q11,Q10), so
// each half's last read phase is deterministic and the staging ledger closes:
//   p0:B(o)hi p1:A(o)hi p2:B(e+2)lo p3:A(e+2)lo p4:B(e+2)hi p5:A(e+2)hi
//   p6:B(o+2)lo p7:A(o+2)lo     (target free: occupant's reads done >=1 BAR prior)
// vmcnt(4) ONLY at p3/p7 ends: retires exactly the next tile's 4 halves, keeps 2
// half-tiles (4 loads) in flight.  Phase = [ds_reads; stage; BAR; setprio MFMA
// setprio; BAR] — reads stay in flight across the pre-MFMA BAR (compiler inserts
// the counted lgkmcnt before use); stages never drain in the main loop.
// Staging: one half-tile/phase by all 512 thr, 2 gld16 each (subtile w and w+8,
// HW adds lane*16; per-lane pre-swizzled SOURCE = proven involution).
#define BAR do { asm volatile("" ::: "memory"); __builtin_amdgcn_s_barrier(); asm volatile("" ::: "memory"); } while (0)

#define STG_A(KT, H, DB) do {                                                   \
    gld16(pAst + (size_t)(H) * 128 * lda + (size_t)(KT) * 64,                   \
          lds + (DB) + (H) * 16384 + dstOff);                                   \
    gld16(pAst + (size_t)((H) * 128 + 64) * lda + (size_t)(KT) * 64,            \
          lds + (DB) + (H) * 16384 + dstOff + 8192);                            \
  } while (0)
#define STG_B(KT, H, DB) do {                                                   \
    gld16(pBst + (size_t)(H) * 128 * ldb + (size_t)(KT) * 64,                   \
          lds + (DB) + 32768 + (H) * 16384 + dstOff);                           \
    gld16(pBst + (size_t)((H) * 128 + 64) * ldb + (size_t)(KT) * 64,            \
          lds + (DB) + 32768 + (H) * 16384 + dstOff + 8192);                    \
  } while (0)

#define RDA8(DB, MH)                                                            \
  { _Pragma("unroll") for (int mm = 0; mm < 4; ++mm)                            \
    _Pragma("unroll") for (int kk = 0; kk < 2; ++kk)                            \
      av[mm][kk] = *(const bf16x8*)(lds + (DB) + (MH) * 16384 +                 \
                    (((wr * 4 + mm) * 2 + kk) << 10) + innerL); }

#define RDB4(DB, NH, BV)                                                        \
  { _Pragma("unroll") for (int nn = 0; nn < 2; ++nn)                            \
    _Pragma("unroll") for (int kk = 0; kk < 2; ++kk)                            \
      BV[nn][kk] = *(const bf16x8*)(lds + (DB) + 32768 + (NH) * 16384 +         \
                    (((wc * 2 + nn) * 2 + kk) << 10) + innerL); }

#define MQ(MH, NH, BV)                                                          \
  { __builtin_amdgcn_s_setprio(1);                                              \
    _Pragma("unroll") for (int kk = 0; kk < 2; ++kk)                            \
    _Pragma("unroll") for (int mm = 0; mm < 4; ++mm)                            \
    _Pragma("unroll") for (int nn = 0; nn < 2; ++nn)                            \
      acc[(MH) * 4 + mm][(NH) * 2 + nn] = __builtin_amdgcn_mfma_f32_16x16x32_bf16( \
          av[mm][kk], BV[nn][kk], acc[(MH) * 4 + mm][(NH) * 2 + nn], 0, 0, 0);  \
    __builtin_amdgcn_s_setprio(0); }

__global__ __launch_bounds__(512, 2) void gemm8p(
    const u16* __restrict__ Ag, const u16* __restrict__ Bg,
    const float* __restrict__ bias, float* __restrict__ C,
    int lda, int ldb, int ldc, int K) {
  __shared__ __align__(1024) char lds[131072];
  const int t = threadIdx.x;
  const int lane = t & 63;
  const int w = t >> 6;
  const int wr = w >> 2, wc = w & 3;
  const int l15 = lane & 15, lhi = lane >> 4;

  // XCD-slab mapping (verified: FETCH 304->203MB)
  const int bid = blockIdx.x;
  const int g = bid >> 3;
  const int tile_m = (bid & 7) * 4 + (g & 3);
  const int tile_n = g >> 2;
  const int brow = tile_m << 8;
  const int bcol = tile_n << 8;

  // staging coords: per-lane pre-swizzled source (proven involution);
  // wave w stages subtile w (rows 0-63 of the half) and w+8 (rows 64-127).
  const int sb = (lane << 4) ^ (lane & 32);
  const int r0 = (w >> 1) * 16 + (sb >> 6);
  const int c0 = (w & 1) * 32 + ((sb & 63) >> 1);
  const u16* pAst = Ag + (size_t)(brow + r0) * lda + c0;
  const u16* pBst = Bg + (size_t)(bcol + r0) * ldb + c0;
  const int dstOff = w << 10;            // wave-uniform; HW adds lane*16

  // fragment read base (proven swizzled-read formula)
  const int innerL = ((l15 << 6) + (lhi << 4)) ^ ((l15 & 8) << 2);

  f32x4 acc[8][4] = {};
  bf16x8 av[4][2], bv[2][2], bv2[2][2];

  const int NT = K >> 6;        // 66
  const int NIT = NT >> 1;      // 33

  // ---- prologue: tile0 (4 halves) + B(1)-lo + A(1)-lo; vmcnt(4) leaves the
  // latter two in flight = steady-state p7-end invariant ----
  STG_A(0, 0, 0); STG_A(0, 1, 0); STG_B(0, 0, 0); STG_B(0, 1, 0);
  STG_B(1, 0, 65536); STG_A(1, 0, 65536);
  asm volatile("s_waitcnt vmcnt(4)" ::: "memory");   // tile 0 landed
  BAR;

  for (int i = 0; i < NIT; ++i) {
    const int e = 2 * i;
    const int o = e + 1;
    const bool st2 = (i + 1 < NIT);      // tiles e+2, o+2 exist
    // ======== phases 0-3: tile e (dbuf0) ========
    // p0: read A-lo + B-lo; stage B(o)-hi
    RDA8(0, 0); RDB4(0, 0, bv);
    STG_B(o, 1, 65536);
    BAR; MQ(0, 0, bv); BAR;
    // p1: read B-hi; stage A(o)-hi
    RDB4(0, 1, bv2);
    STG_A(o, 1, 65536);
    BAR; MQ(0, 1, bv2); BAR;
    // p2: read A-hi; stage B(e+2)-lo (db0.B-lo reads done @p0)
    RDA8(0, 1);
    if (st2) STG_B(e + 2, 0, 0);
    BAR; MQ(1, 1, bv2); BAR;
    // p3: stage A(e+2)-lo (db0.A-lo reads done @p0); vmcnt retires tile o
    if (st2) STG_A(e + 2, 0, 0);
    if (st2) { asm volatile("s_waitcnt vmcnt(4)" ::: "memory"); }
    else     { asm volatile("s_waitcnt vmcnt(0)" ::: "memory"); }
    BAR; MQ(1, 0, bv); BAR;
    // ======== phases 4-7: tile o (dbuf1) ========
    // p4: read A-lo + B-lo; stage B(e+2)-hi (db0.B-hi reads done @p1)
    RDA8(65536, 0); RDB4(65536, 0, bv);
    if (st2) STG_B(e + 2, 1, 0);
    BAR; MQ(0, 0, bv); BAR;
    // p5: read B-hi; stage A(e+2)-hi (db0.A-hi reads done @p2)
    RDB4(65536, 1, bv2);
    if (st2) STG_A(e + 2, 1, 0);
    BAR; MQ(0, 1, bv2); BAR;
    // p6: read A-hi; stage B(o+2)-lo (db1.B-lo reads done @p4)
    RDA8(65536, 1);
    if (st2) STG_B(o + 2, 0, 65536);
    BAR; MQ(1, 1, bv2); BAR;
    // p7: stage A(o+2)-lo (db1.A-lo reads done @p4); vmcnt retires tile e+2
    if (st2) STG_A(o + 2, 0, 65536);
    asm volatile("s_waitcnt vmcnt(4)" ::: "memory");   // no-op at tail
    BAR; MQ(1, 0, bv); BAR;
  }

  // ---- epilogue: C = acc + bias ----
  // row = brow + mh*128 + wr*64 + m*16 + lhi*4 + jj ; col = bcol + nh*128 + wc*32 + n*16 + l15
#pragma unroll
  for (int mi = 0; mi < 8; ++mi) {
    const int row0 = brow + (mi >> 2) * 128 + wr * 64 + (mi & 3) * 16 + lhi * 4;
#pragma unroll
    for (int ni = 0; ni < 4; ++ni) {
      const int col = bcol + (ni >> 1) * 128 + wc * 32 + (ni & 1) * 16 + l15;
      const float b2 = bias[col];
#pragma unroll
      for (int jj = 0; jj < 4; ++jj)
        C[(size_t)(row0 + jj) * ldc + col] = acc[mi][ni][jj] + b2;
    }
  }
}

// ---------- launch ----------
extern "C" void kernel_launch(void* const* d_in, const int* in_sizes, int n_in,
                              void* d_out, int out_size, void* d_ws, size_t ws_size,
                              hipStream_t stream) {
  const float* x  = (const float*)d_in[0];   // [8192][4096]
  const float* Wb = (const float*)d_in[1];   // [4096][4096]
  const float* bb = (const float*)d_in[2];   // [4096]
  const float* Wg = (const float*)d_in[3];   // [8][4096]
  const float* A  = (const float*)d_in[4];   // [8][16][4096] = [128][4096]
  const float* B  = (const float*)d_in[5];   // [8][4096][16]
  float* out = (float*)d_out;                // [8192][4096]

  char* ws = (char*)d_ws;
  u16*   Xaug = (u16*)ws;                                     // 8192 x 4224 bf16
  u16*   Waug = (u16*)(ws + 69206016);                        // 4096 x 4224 bf16
  u16*   a2   = (u16*)(ws + 69206016 + 34603008);             // 128 x 4096 bf16
  float* wsc  = (float*)(ws + 69206016 + 34603008 + 1048576); // 8192 x 8

  // 1) all input-only work (r15 contiguous mapping — r16 interleave regressed)
  fused_pre<<<3072, 256, 0, stream>>>(x, Wg, Wb, B, A, Xaug, Waug, a2, wsc);

  // 2) lora down-proj + gate-scale
  lora_hw<<<256, 256, 0, stream>>>(Xaug, a2, wsc, Xaug);

  // 3) main fused GEMM: out = Xaug @ Waug^T + bias (m201 8-phase port)
  gemm8p<<<512, 512, 0, stream>>>(Xaug, Waug, bb, out, 4224, 4224, 4096, 4224);
}

// Round 18
// 330.675 us; speedup vs baseline: 1.1183x; 1.0250x over previous
//
#include <hip/hip_runtime.h>
#include <stdint.h>

typedef unsigned short u16;
typedef float f32x4 __attribute__((ext_vector_type(4)));
typedef short bf16x8 __attribute__((ext_vector_type(8)));

// ---------- helpers ----------
static __device__ __forceinline__ u16 f2bf(float f) {
  union { float f; unsigned u; } a; a.f = f;
  unsigned r = a.u + 0x7fffu + ((a.u >> 16) & 1u);   // round-nearest-even
  return (u16)(r >> 16);
}

static __device__ __forceinline__ void gld16(const void* g, void* l) {
  __builtin_amdgcn_global_load_lds(
      (const __attribute__((address_space(1))) void*)(uintptr_t)g,
      (__attribute__((address_space(3))) void*)(uintptr_t)l,
      16, 0, 0);
}

// ================== K1: all input-only work (VERBATIM r15 — best, 331us) ==================
__global__ __launch_bounds__(256, 4) void fused_pre(
    const float* __restrict__ x, const float* __restrict__ Wg,
    const float* __restrict__ Wb, const float* __restrict__ B,
    const float* __restrict__ A,
    u16* __restrict__ Xaug, u16* __restrict__ Waug, u16* __restrict__ a2,
    float* __restrict__ wsc) {
  const int bid = blockIdx.x;
  const int t = threadIdx.x;
  if (bid < 512) {
    const int lane = t & 63;
    const int wv = t >> 6;
    const int n0 = bid * 16 + wv * 4;
    const float4* g4 = (const float4*)Wg;      // [8][1024] float4
    float acc[4][8] = {};
#pragma unroll 2
    for (int ii = 0; ii < 16; ++ii) {
      const int i = ii * 64 + lane;
      float4 xv[4];
#pragma unroll
      for (int tok = 0; tok < 4; ++tok) {
        xv[tok] = *(const float4*)(x + (size_t)(n0 + tok) * 4096 + i * 4);
        ushort4 o;
        o.x = f2bf(xv[tok].x); o.y = f2bf(xv[tok].y);
        o.z = f2bf(xv[tok].z); o.w = f2bf(xv[tok].w);
        *(ushort4*)(Xaug + (size_t)(n0 + tok) * 4224 + i * 4) = o;
      }
#pragma unroll
      for (int e = 0; e < 8; ++e) {
        float4 w4 = g4[e * 1024 + i];
#pragma unroll
        for (int tok = 0; tok < 4; ++tok)
          acc[tok][e] += xv[tok].x * w4.x + xv[tok].y * w4.y +
                         xv[tok].z * w4.z + xv[tok].w * w4.w;
      }
    }
#pragma unroll
    for (int tok = 0; tok < 4; ++tok) {
#pragma unroll
      for (int e = 0; e < 8; ++e) {
#pragma unroll
        for (int off = 32; off > 0; off >>= 1)
          acc[tok][e] += __shfl_xor(acc[tok][e], off);
      }
      int i1 = 0; float m1 = acc[tok][0];
#pragma unroll
      for (int e = 1; e < 8; ++e) if (acc[tok][e] > m1) { m1 = acc[tok][e]; i1 = e; }
      int i2 = -1; float m2 = -3.4e38f;
#pragma unroll
      for (int e = 0; e < 8; ++e)
        if (e != i1 && acc[tok][e] > m2) { m2 = acc[tok][e]; i2 = e; }
      float w1 = 1.0f / (1.0f + expf(m2 - m1));   // p1/(p1+p2) softmax+renorm
      float w2 = 1.0f - w1;
      if (lane < 8)
        wsc[(size_t)(n0 + tok) * 8 + lane] =
            (lane == i1) ? w1 : ((lane == i2) ? w2 : 0.0f);
    }
  } else if (bid < 2560) {
    const int total = 4096 * 1056;               // vec4 groups
    for (int v = (bid - 512) * 256 + t; v < total; v += 2048 * 256) {
      const int o = v / 1056;
      const int c = (v - o * 1056) * 4;
      ushort4 out;
      if (c < 4096) {
        float4 w = *(const float4*)(Wb + (size_t)o * 4096 + c);
        out.x = f2bf(w.x); out.y = f2bf(w.y); out.z = f2bf(w.z); out.w = f2bf(w.w);
      } else {
        const int er = c - 4096;
        const int e = er >> 4;
        const int r = er & 15;
        const float* bp = B + ((size_t)e * 4096 + o) * 16 + r;
        out.x = f2bf(bp[0] * 2.0f); out.y = f2bf(bp[1] * 2.0f);
        out.z = f2bf(bp[2] * 2.0f); out.w = f2bf(bp[3] * 2.0f);
      }
      *(ushort4*)(Waug + (size_t)o * 4224 + c) = out;
    }
  } else {
    const int i = (bid - 2560) * 256 + t;        // 0..131071 vec4 groups
    const size_t e = (size_t)i * 4;
    float4 v = *(const float4*)(A + e);
    ushort4 o;
    o.x = f2bf(v.x); o.y = f2bf(v.y); o.z = f2bf(v.z); o.w = f2bf(v.w);
    *(ushort4*)(a2 + e) = o;
  }
}

// ================== K2: LoRA down-proj + gate-scale (VERBATIM r15, proven) ==================
__global__ __launch_bounds__(256) void lora_hw(
    const u16* __restrict__ Xa, const u16* __restrict__ A2,
    const float* __restrict__ wsc, u16* __restrict__ Xaug) {
  __shared__ __align__(1024) char lds[40960];
  const int t = threadIdx.x;
  const int lane = t & 63;
  const int w = t >> 6;
  const int l15 = lane & 15, lhi = lane >> 4;
  const int brow = blockIdx.x * 32;

  const int sb = (lane << 4) ^ (lane & 32);
  const int srow = sb >> 6;
  const int scol = (sb & 63) >> 1;

  const u16* pA = Xa + (size_t)(brow + (w >> 1) * 16 + srow) * 4224 + (w & 1) * 32 + scol;
  const u16* pB[4];
#pragma unroll
  for (int s = 0; s < 4; ++s) {
    const int idx = w * 4 + s;
    pB[s] = A2 + (size_t)((idx >> 1) * 16 + srow) * 4096 + (idx & 1) * 32 + scol;
  }
  const int dA = w << 10;
  const int dB = 4096 + (w << 12);
  const int innerL = ((l15 << 6) + (lhi << 4)) ^ ((l15 & 8) << 2);

  f32x4 acc[2][2] = {};

  gld16(pA, lds + dA);
#pragma unroll
  for (int s = 0; s < 4; ++s) gld16(pB[s], lds + dB + (s << 10));

  for (int j = 0; j < 64; ++j) {
    const int buf = (j & 1) * 20480;
    const int obuf = buf ^ 20480;
    if (j < 63) {
      const int k1 = (j + 1) * 64;
      gld16(pA + k1, lds + obuf + dA);
#pragma unroll
      for (int s = 0; s < 4; ++s) gld16(pB[s] + k1, lds + obuf + dB + (s << 10));
      asm volatile("s_waitcnt vmcnt(5)" ::: "memory");   // tile j landed
    } else {
      asm volatile("s_waitcnt vmcnt(0)" ::: "memory");
    }
    __syncthreads();
    bf16x8 av[2][2], bv[2][2];
#pragma unroll
    for (int m = 0; m < 2; ++m)
#pragma unroll
      for (int kk = 0; kk < 2; ++kk)
        av[m][kk] = *(const bf16x8*)(lds + buf + ((m * 2 + kk) << 10) + innerL);
#pragma unroll
    for (int n = 0; n < 2; ++n)
#pragma unroll
      for (int kk = 0; kk < 2; ++kk)
        bv[n][kk] = *(const bf16x8*)(lds + buf + 4096 + (((w * 2 + n) * 2 + kk) << 10) + innerL);
#pragma unroll
    for (int kk = 0; kk < 2; ++kk)
#pragma unroll
      for (int m = 0; m < 2; ++m)
#pragma unroll
        for (int n = 0; n < 2; ++n)
          acc[m][n] = __builtin_amdgcn_mfma_f32_16x16x32_bf16(av[m][kk], bv[n][kk], acc[m][n], 0, 0, 0);
    __syncthreads();
  }
#pragma unroll
  for (int m = 0; m < 2; ++m) {
    const int rbase = brow + m * 16 + lhi * 4;
#pragma unroll
    for (int n = 0; n < 2; ++n) {
      const int col = w * 32 + n * 16 + l15;
#pragma unroll
      for (int j = 0; j < 4; ++j) {
        const int row = rbase + j;
        const float g = wsc[(size_t)row * 8 + (col >> 4)];
        Xaug[(size_t)row * 4224 + 4096 + col] = f2bf(acc[m][n][j] * g);
      }
    }
  }
}

// ================== 256x256 main GEMM (r12 schedule; A-stage@p0, B-stage@p2) ==================
// r12's proven 4-barrier pipelined-read schedule (best of 8 variants, 237us).
// Only delta: all 4 A(j+1) gld16 issue at p0 (was 2+2 p0/p1), all 4 B(j+2) at p2
// (was 2+2 p2/p3).  vmcnt ledger UNCHANGED: at p3, in flight = B(j+1)4 + A(j+1)4
// + B(j+2)4 = 12; vmcnt(4) retires 8 oldest (B(j+1),A(j+1)), keeps B(j+2)4.
// WAR windows are supersets of r12's (writes same-or-earlier phase, >=1 barrier
// after occupant reads complete).  Gains issue-to-wait slack: A youngest 2->3 phases.
#define BAR do { asm volatile("" ::: "memory"); __builtin_amdgcn_s_barrier(); asm volatile("" ::: "memory"); } while (0)

#define RDA(BUF, MH)                                                            \
  { _Pragma("unroll") for (int mm = 0; mm < 4; ++mm)                            \
    _Pragma("unroll") for (int kk = 0; kk < 2; ++kk)                            \
      av[mm][kk] = *(const bf16x8*)(lds + (BUF) + fbA + ((((MH) * 4 + mm) * 2 + kk) << 10)); }

#define RDB(BUF, NH)                                                            \
  { _Pragma("unroll") for (int nn = 0; nn < 2; ++nn)                            \
    _Pragma("unroll") for (int kk = 0; kk < 2; ++kk)                            \
      bv[(NH) * 2 + nn][kk] = *(const bf16x8*)(lds + (BUF) + fbB + ((((NH) * 2 + nn) * 2 + kk) << 10)); }

#define MFMAQ(MH, NH)                                                           \
  { __builtin_amdgcn_s_setprio(1);                                              \
    _Pragma("unroll") for (int kk = 0; kk < 2; ++kk)                            \
    _Pragma("unroll") for (int mm = 0; mm < 4; ++mm)                            \
    _Pragma("unroll") for (int nn = 0; nn < 2; ++nn)                            \
      acc[(MH) * 4 + mm][(NH) * 2 + nn] = __builtin_amdgcn_mfma_f32_16x16x32_bf16( \
          av[mm][kk], bv[(NH) * 2 + nn][kk], acc[(MH) * 4 + mm][(NH) * 2 + nn], 0, 0, 0); \
    __builtin_amdgcn_s_setprio(0); }

__global__ __launch_bounds__(512, 2) void gemm8p(
    const u16* __restrict__ Ag, const u16* __restrict__ Bg,
    const float* __restrict__ bias, float* __restrict__ C,
    int lda, int ldb, int ldc, int K) {
  __shared__ __align__(1024) char lds[131072];
  const int t = threadIdx.x;
  const int lane = t & 63;
  const int w = t >> 6;
  const int wr = w >> 2, wc = w & 3;
  const int l15 = lane & 15, lhi = lane >> 4;

  // XCD-slab mapping (verified: FETCH 304->203MB)
  const int bid = blockIdx.x;
  const int g = bid >> 3;
  const int tile_m = (bid & 7) * 4 + (g & 3);
  const int tile_n = g >> 2;
  const int brow = tile_m << 8;
  const int bcol = tile_n << 8;

  // pre-swizzled per-lane source coords (st_16x32 involution)
  const int sb = (lane << 4) ^ (lane & 32);
  const int srow = sb >> 6;
  const int scol = (sb & 63) >> 1;

  const u16* pA[4]; const u16* pB[4];
#pragma unroll
  for (int s = 0; s < 4; ++s) {
    const int idx = w * 4 + s;
    const int rg = idx >> 1, cs = idx & 1;
    pA[s] = Ag + (size_t)(brow + rg * 16 + srow) * lda + cs * 32 + scol;
    pB[s] = Bg + (size_t)(bcol + rg * 16 + srow) * ldb + cs * 32 + scol;
  }
  const int ldsA = w << 12;
  const int ldsB = 32768 + (w << 12);

  const int innerL = ((l15 << 6) + (lhi << 4)) ^ ((l15 & 8) << 2);
  const int fbA = (wr << 14) + innerL;
  const int fbB = 32768 + (wc << 13) + innerL;

  f32x4 acc[8][4] = {};
  bf16x8 av[4][2], bv[4][2];

  const int NT = K >> 6;   // 66 K-tiles

#pragma unroll
  for (int s = 0; s < 4; ++s) gld16(pA[s], lds + ldsA + (s << 10));
#pragma unroll
  for (int s = 0; s < 4; ++s) gld16(pB[s], lds + ldsB + (s << 10));
#pragma unroll
  for (int s = 0; s < 4; ++s) gld16(pB[s] + 64, lds + 65536 + ldsB + (s << 10));
#pragma unroll
  for (int s = 0; s < 4; ++s) { pA[s] += 64; pB[s] += 128; }
  asm volatile("s_waitcnt vmcnt(4)" ::: "memory");   // A(0),B(0) landed
  BAR;
  RDA(0, 0); RDB(0, 0);    // av0(0), bv01(0) for first M0

  for (int j = 0; j < NT; ++j) {
    const int buf  = (j & 1) << 16;
    const int obuf = buf ^ 65536;
    const bool stA = (j + 1 < NT);
    const bool stB = (j + 2 < NT);
    // p0: stage ALL of A(j+1); M0 [av0,bv01]; read bv23 (regs free)
    if (stA) {
#pragma unroll
      for (int s = 0; s < 4; ++s) gld16(pA[s], lds + obuf + ldsA + (s << 10));
    }
    MFMAQ(0, 0);
    RDB(buf, 1);
    BAR;
    // p1: M1 [av0,bv23]; read av1 (av regs die at M1 issue)
    MFMAQ(0, 1);
    RDA(buf, 1);
    BAR;
    // p2: stage ALL of B(j+2) -> this buf (bv01 consumed at M0, bv23 at M1); M2
    if (stB) {
#pragma unroll
      for (int s = 0; s < 4; ++s) gld16(pB[s], lds + buf + ldsB + (s << 10));
    }
    MFMAQ(1, 1);
    BAR;
    // p3: vmcnt(4)+BAR (A(j+1),B(j+1) landed; B(j+2)4 stays in flight);
    //     M3 [av1,bv01]; read av0',bv01' from next buf
    if (j < NT - 2)       { asm volatile("s_waitcnt vmcnt(4)" ::: "memory"); }
    else if (j == NT - 2) { asm volatile("s_waitcnt vmcnt(0)" ::: "memory"); }
    BAR;
    MFMAQ(1, 0);
    if (stA) { RDA(obuf, 0); RDB(obuf, 0); }
#pragma unroll
    for (int s = 0; s < 4; ++s) { pA[s] += 64; pB[s] += 64; }
  }

#pragma unroll
  for (int m = 0; m < 8; ++m) {
    const int row0 = brow + wr * 128 + m * 16 + lhi * 4;
#pragma unroll
    for (int n = 0; n < 4; ++n) {
      const int col = bcol + wc * 64 + n * 16 + l15;
      const float b2 = bias[col];
#pragma unroll
      for (int jj = 0; jj < 4; ++jj)
        C[(size_t)(row0 + jj) * ldc + col] = acc[m][n][jj] + b2;
    }
  }
}

// ---------- launch ----------
extern "C" void kernel_launch(void* const* d_in, const int* in_sizes, int n_in,
                              void* d_out, int out_size, void* d_ws, size_t ws_size,
                              hipStream_t stream) {
  const float* x  = (const float*)d_in[0];   // [8192][4096]
  const float* Wb = (const float*)d_in[1];   // [4096][4096]
  const float* bb = (const float*)d_in[2];   // [4096]
  const float* Wg = (const float*)d_in[3];   // [8][4096]
  const float* A  = (const float*)d_in[4];   // [8][16][4096] = [128][4096]
  const float* B  = (const float*)d_in[5];   // [8][4096][16]
  float* out = (float*)d_out;                // [8192][4096]

  char* ws = (char*)d_ws;
  u16*   Xaug = (u16*)ws;                                     // 8192 x 4224 bf16
  u16*   Waug = (u16*)(ws + 69206016);                        // 4096 x 4224 bf16
  u16*   a2   = (u16*)(ws + 69206016 + 34603008);             // 128 x 4096 bf16
  float* wsc  = (float*)(ws + 69206016 + 34603008 + 1048576); // 8192 x 8

  // 1) all input-only work (r15 contiguous mapping — best measured)
  fused_pre<<<3072, 256, 0, stream>>>(x, Wg, Wb, B, A, Xaug, Waug, a2, wsc);

  // 2) lora down-proj + gate-scale
  lora_hw<<<256, 256, 0, stream>>>(Xaug, a2, wsc, Xaug);

  // 3) main fused GEMM: out = Xaug @ Waug^T + bias (r12 schedule, staging repacked)
  gemm8p<<<512, 512, 0, stream>>>(Xaug, Waug, bb, out, 4224, 4224, 4096, 4224);
}